// Round 1
// baseline (5705.519 us; speedup 1.0000x reference)
//
#include <hip/hip_runtime.h>

#define CDIV(a,b) (((a)+(b)-1)/(b))

// ---------------- wave/block reductions ----------------
__device__ __forceinline__ float waveSum(float v){
#pragma unroll
  for(int o=32;o;o>>=1) v += __shfl_xor(v,o);
  return v;
}
__device__ __forceinline__ float waveMax(float v){
#pragma unroll
  for(int o=32;o;o>>=1) v = fmaxf(v,__shfl_xor(v,o));
  return v;
}

// ---------------- generic tiled GEMMs (f32) ----------------
// C[M,N] = act(scale*(A[M,K] @ W[N,K]^T) + bias[N])
template<int ACT>
__global__ __launch_bounds__(256)
void gemm_nt(const float* __restrict__ A, int lda,
             const float* __restrict__ W, int ldw,
             float* __restrict__ C, int ldc,
             const float* __restrict__ bias,
             int M, int N, int K, float scale)
{
  __shared__ float As[16][68];
  __shared__ float Ws[16][68];
  const int bm = blockIdx.x*64, bn = blockIdx.y*64;
  const int tid = threadIdx.x;
  const int lr = tid>>2;          // 0..63
  const int kq = (tid&3)<<2;      // 0,4,8,12
  const int tx = tid&15, ty = tid>>4;
  float acc[4][4] = {};
  for(int k0=0;k0<K;k0+=16){
    float4 av = make_float4(0.f,0.f,0.f,0.f), wv = make_float4(0.f,0.f,0.f,0.f);
    if(bm+lr < M && k0+kq < K) av = *reinterpret_cast<const float4*>(A + (size_t)(bm+lr)*lda + k0+kq);
    if(bn+lr < N && k0+kq < K) wv = *reinterpret_cast<const float4*>(W + (size_t)(bn+lr)*ldw + k0+kq);
    As[kq+0][lr]=av.x; As[kq+1][lr]=av.y; As[kq+2][lr]=av.z; As[kq+3][lr]=av.w;
    Ws[kq+0][lr]=wv.x; Ws[kq+1][lr]=wv.y; Ws[kq+2][lr]=wv.z; Ws[kq+3][lr]=wv.w;
    __syncthreads();
#pragma unroll
    for(int k=0;k<16;k++){
      float4 a4 = *reinterpret_cast<const float4*>(&As[k][ty<<2]);
      float4 w4 = *reinterpret_cast<const float4*>(&Ws[k][tx<<2]);
      float aa[4]={a4.x,a4.y,a4.z,a4.w};
      float ww[4]={w4.x,w4.y,w4.z,w4.w};
#pragma unroll
      for(int i=0;i<4;i++)
#pragma unroll
        for(int j=0;j<4;j++) acc[i][j] = fmaf(aa[i],ww[j],acc[i][j]);
    }
    __syncthreads();
  }
#pragma unroll
  for(int i=0;i<4;i++){
    int row = bm + (ty<<2) + i;
    if(row>=M) continue;
#pragma unroll
    for(int j=0;j<4;j++){
      int col = bn + (tx<<2) + j;
      if(col>=N) continue;
      float v = acc[i][j]*scale + (bias? bias[col] : 0.f);
      if(ACT==1) v = 0.5f*v*(1.f+erff(v*0.70710678118654752f));
      C[(size_t)row*ldc+col]=v;
    }
  }
}

// C[M,N] = scale*(A[M,K] @ B[K,N])   (no bias, no act)
__global__ __launch_bounds__(256)
void gemm_nn(const float* __restrict__ A, int lda,
             const float* __restrict__ Bm, int ldb,
             float* __restrict__ C, int ldc,
             int M, int N, int K, float scale)
{
  __shared__ float As[16][68];
  __shared__ float Bs[16][68];
  const int bm = blockIdx.x*64, bn = blockIdx.y*64;
  const int tid = threadIdx.x;
  const int lr = tid>>2;
  const int kq = (tid&3)<<2;
  const int kr = tid>>4;          // 0..15 (B row within tile)
  const int nq = (tid&15)<<2;     // 0..60
  const int tx = tid&15, ty = tid>>4;
  float acc[4][4] = {};
  for(int k0=0;k0<K;k0+=16){
    float4 av = make_float4(0.f,0.f,0.f,0.f), bv = make_float4(0.f,0.f,0.f,0.f);
    if(bm+lr < M && k0+kq < K) av = *reinterpret_cast<const float4*>(A + (size_t)(bm+lr)*lda + k0+kq);
    if(k0+kr < K && bn+nq < N) bv = *reinterpret_cast<const float4*>(Bm + (size_t)(k0+kr)*ldb + bn+nq);
    As[kq+0][lr]=av.x; As[kq+1][lr]=av.y; As[kq+2][lr]=av.z; As[kq+3][lr]=av.w;
    Bs[kr][nq+0]=bv.x; Bs[kr][nq+1]=bv.y; Bs[kr][nq+2]=bv.z; Bs[kr][nq+3]=bv.w;
    __syncthreads();
#pragma unroll
    for(int k=0;k<16;k++){
      float4 a4 = *reinterpret_cast<const float4*>(&As[k][ty<<2]);
      float4 b4 = *reinterpret_cast<const float4*>(&Bs[k][tx<<2]);
      float aa[4]={a4.x,a4.y,a4.z,a4.w};
      float bb[4]={b4.x,b4.y,b4.z,b4.w};
#pragma unroll
      for(int i=0;i<4;i++)
#pragma unroll
        for(int j=0;j<4;j++) acc[i][j] = fmaf(aa[i],bb[j],acc[i][j]);
    }
    __syncthreads();
  }
#pragma unroll
  for(int i=0;i<4;i++){
    int row = bm + (ty<<2) + i;
    if(row>=M) continue;
#pragma unroll
    for(int j=0;j<4;j++){
      int col = bn + (tx<<2) + j;
      if(col>=N) continue;
      C[(size_t)row*ldc+col]=acc[i][j]*scale;
    }
  }
}

// ---------------- LayerNorm(x + t) over 384, row-per-block (128 thr) ----------------
__global__ __launch_bounds__(128)
void add_ln(const float* __restrict__ X, const float* __restrict__ T,
            float* __restrict__ O, const float* __restrict__ g,
            const float* __restrict__ be, int M)
{
  int row = blockIdx.x;
  if(row>=M) return;
  const float* x = X + (size_t)row*384;
  const float* t = T + (size_t)row*384;
  float* o = O + (size_t)row*384;
  int tid = threadIdx.x;
  float v[3]; float s=0.f;
#pragma unroll
  for(int i=0;i<3;i++){ int c = tid + i*128; v[i] = x[c] + t[c]; s += v[i]; }
  s = waveSum(s);
  __shared__ float p1[2];
  if((tid&63)==0) p1[tid>>6]=s;
  __syncthreads();
  float mean = (p1[0]+p1[1])*(1.f/384.f);
  float vs=0.f;
#pragma unroll
  for(int i=0;i<3;i++){ float d=v[i]-mean; vs += d*d; }
  vs = waveSum(vs);
  __shared__ float p2[2];
  if((tid&63)==0) p2[tid>>6]=vs;
  __syncthreads();
  float rstd = rsqrtf((p2[0]+p2[1])*(1.f/384.f) + 1e-5f);
#pragma unroll
  for(int i=0;i<3;i++){ int c = tid + i*128; o[c] = (v[i]-mean)*rstd*g[c] + be[c]; }
}

// ---------------- generic row softmax (in place), row-per-block (256 thr) --------
__global__ __launch_bounds__(256)
void softmax_rows(float* __restrict__ X, int cols)
{
  float* x = X + (size_t)blockIdx.x*cols;
  int tid = threadIdx.x;
  float m = -1e30f;
  for(int c=tid;c<cols;c+=256) m = fmaxf(m, x[c]);
  m = waveMax(m);
  __shared__ float sm[4];
  if((tid&63)==0) sm[tid>>6]=m;
  __syncthreads();
  m = fmaxf(fmaxf(sm[0],sm[1]),fmaxf(sm[2],sm[3]));
  float s=0.f;
  for(int c=tid;c<cols;c+=256){ float e = expf(x[c]-m); x[c]=e; s+=e; }
  s = waveSum(s);
  __shared__ float ss[4];
  if((tid&63)==0) ss[tid>>6]=s;
  __syncthreads();
  s = ss[0]+ss[1]+ss[2]+ss[3];
  float inv = 1.f/s;
  for(int c=tid;c<cols;c+=256) x[c]*=inv;
}

// ---------------- misc small kernels ----------------
__global__ void prep_conv(const float* __restrict__ cw, float* __restrict__ W0, float* __restrict__ W1){
  int gid = blockIdx.x*256+threadIdx.x;
  if(gid >= 384*384) return;
  int i = gid % 384, o = gid / 384;
  const float* w = cw + (size_t)gid*3;   // (o*384+i)*3
  W0[(size_t)o*768 + i]       = w[1];
  W0[(size_t)o*768 + 384 + i] = w[2];
  W1[(size_t)o*768 + i]       = w[0];
  W1[(size_t)o*768 + 384 + i] = w[1];
}

__global__ void seq_init(const int* __restrict__ inp, const float* __restrict__ emb,
                         const float* __restrict__ rp, float* __restrict__ seq){
  int gid = blockIdx.x*256+threadIdx.x;
  if(gid >= 128*8*384) return;
  int j = gid % 384; int l = (gid/384) & 7; int b = gid / 3072;
  int tok = inp[b*8 + l];
  seq[gid] = emb[(size_t)tok*384 + j] + rp[l*384 + j];
}

__global__ void build_pairs(const float* __restrict__ seq, const float* __restrict__ rp,
                            float* __restrict__ pairs, int N, int P){
  int gid = blockIdx.x*256+threadIdx.x;
  if(gid >= N*768) return;
  int c = gid % 768; int n = gid / 768;
  int t = c / 384; int j = c % 384;
  int i = n % P; int b = n / P;
  pairs[gid] = seq[((size_t)b*8 + i + t)*384 + j] + rp[t*384 + j];
}

// pair attention (len 2, HP=4, dh=96): probs[((n*4+h)*2+t)*2 + t']
__global__ void attn2_scores(const float* __restrict__ QKV, float* __restrict__ probs, int N){
  int gid = blockIdx.x*256 + threadIdx.x;
  if(gid >= N*8) return;
  int t = gid & 1; int h = (gid>>1) & 3; int n = gid>>3;
  const float* q  = QKV + ((size_t)(n*2+t))*1152 + h*96;
  const float* k0 = QKV + ((size_t)(n*2+0))*1152 + 384 + h*96;
  const float* k1 = k0 + 1152;
  float s0=0.f, s1=0.f;
#pragma unroll 8
  for(int d=0;d<96;d++){ float qd=q[d]; s0=fmaf(qd,k0[d],s0); s1=fmaf(qd,k1[d],s1); }
  const float sc = 0.1020620726159658f;   // 1/sqrt(96)
  s0*=sc; s1*=sc;
  float m=fmaxf(s0,s1);
  float e0=expf(s0-m), e1=expf(s1-m);
  float inv=1.f/(e0+e1);
  float* p = probs + (size_t)gid*2;
  p[0]=e0*inv; p[1]=e1*inv;
}

__global__ void attn2_pv(const float* __restrict__ QKV, const float* __restrict__ probs,
                         float* __restrict__ O, int N){
  int gid = blockIdx.x*256 + threadIdx.x;
  if(gid >= N*2*384) return;
  int j = gid % 384; int r = gid / 384;
  int n = r >> 1, t = r & 1; int h = j / 96;
  const float* p = probs + (((size_t)n*4+h)*2+t)*2;
  float v0 = QKV[(size_t)(n*2+0)*1152 + 768 + j];
  float v1 = QKV[(size_t)(n*2+1)*1152 + 768 + j];
  O[gid] = p[0]*v0 + p[1]*v1;
}

// sigmoid(hid . w + b) per pair row; one wave per row
__global__ __launch_bounds__(64)
void score_rows(const float* __restrict__ X, const float* __restrict__ w,
                const float* __restrict__ b0, float* __restrict__ sc, int N){
  int n = blockIdx.x;
  if(n>=N) return;
  const float* x = X + ((size_t)n*2+1)*384;
  int tid = threadIdx.x;
  float s=0.f;
#pragma unroll
  for(int i=0;i<6;i++){ int c = tid + i*64; s = fmaf(x[c], w[c], s); }
  s = waveSum(s);
  if(tid==0) sc[n] = 1.f/(1.f+expf(-(s + b0[0])));
}

// per-batch argmax + entropy of softmax(sc); writes loss column
__global__ void argmax_ent(const float* __restrict__ sc, int P, int* __restrict__ idx,
                           float* __restrict__ loss_slot){
  int b = threadIdx.x;
  if(b>=128) return;
  const float* s = sc + (size_t)b*P;
  float m = s[0]; int am = 0;
  for(int i=1;i<P;i++){ float v=s[i]; if(v>m){m=v;am=i;} }
  float z=0.f, sx=0.f;
  for(int i=0;i<P;i++){ float e=expf(s[i]-m); z+=e; sx=fmaf(e,s[i],sx); }
  float logZ = m + logf(z);
  idx[b]=am;
  loss_slot[(size_t)b*9] = logZ - sx/z;
}

__global__ void gather_sel(const float* __restrict__ X, const int* __restrict__ idx,
                           float* __restrict__ sel, int P){
  int gid = blockIdx.x*256+threadIdx.x;
  if(gid >= 128*384) return;
  int j = gid % 384; int b = gid / 384;
  sel[gid] = X[(((size_t)b*P + idx[b])*2 + 1)*384 + j];
}

// fuse attention: scores over 501 keys (500 precomputed mem + 1 per-batch)
__global__ void fuse_scores(const float* __restrict__ q1, const float* __restrict__ K1,
                            const float* __restrict__ ksel, float* __restrict__ out){
  int gid = blockIdx.x*256+threadIdx.x;
  if(gid >= 128*6*501) return;
  int j = gid % 501; int bh = gid / 501; int h = bh % 6; int b = bh / 6;
  const float* q = q1 + (size_t)b*384 + h*64;
  const float* k = (j<500) ? K1 + (size_t)j*384 + h*64 : ksel + (size_t)b*384 + h*64;
  float s=0.f;
#pragma unroll
  for(int d=0;d<64;d++) s = fmaf(q[d],k[d],s);
  out[(size_t)bh*501 + j] = s*0.125f;
}

__global__ void fuse_pv(const float* __restrict__ p, const float* __restrict__ V1,
                        const float* __restrict__ vsel, float* __restrict__ O){
  int gid = blockIdx.x*256+threadIdx.x;
  if(gid >= 128*384) return;
  int jf = gid % 384; int b = gid / 384; int h = jf >> 6;
  const float* pr = p + ((size_t)b*6+h)*501;
  float acc=0.f;
  for(int j=0;j<500;j++) acc = fmaf(pr[j], V1[(size_t)j*384+jf], acc);
  acc = fmaf(pr[500], vsel[(size_t)b*384+jf], acc);
  O[gid]=acc;
}

__global__ void merge_seq(const float* __restrict__ src, const float* __restrict__ fused,
                          const int* __restrict__ idx, float* __restrict__ dst, int P){
  int gid = blockIdx.x*256+threadIdx.x;
  if(gid >= 128*P*384) return;
  int j = gid % 384; int rest = gid / 384; int i = rest % P; int b = rest / P;
  int id = idx[b];
  float v;
  if(i == id) v = fused[(size_t)b*384 + j];
  else        v = src[((size_t)b*8 + i + (i>id ? 1:0))*384 + j];
  dst[((size_t)b*8 + i)*384 + j] = v;
}

__global__ void zero_loss6(float* __restrict__ lossBase){
  int b = threadIdx.x;
  if(b<128) lossBase[(size_t)b*9 + 6] = 0.f;
}

__global__ void compact_seq(const float* __restrict__ seq, float* __restrict__ out){
  int gid = blockIdx.x*256+threadIdx.x;
  if(gid >= 256*384) return;
  int j = gid % 384; int r = gid / 384; int b = r>>1; int t = r&1;
  out[gid] = seq[((size_t)b*8 + t)*384 + j];
}

// final attention: 502 keys (500 mem + 2 per-batch seq rows)
__global__ void fin_scores(const float* __restrict__ q1, const float* __restrict__ K1,
                           const float* __restrict__ kseq, float* __restrict__ out){
  int gid = blockIdx.x*256+threadIdx.x;
  if(gid >= 256*6*502) return;
  int j = gid % 502; int bth = gid / 502; int h = bth % 6; int bt = bth / 6;
  int b = bt >> 1;
  const float* q = q1 + (size_t)bt*384 + h*64;
  const float* k = (j<500) ? K1 + (size_t)j*384 + h*64
                           : kseq + ((size_t)b*2 + (j-500))*384 + h*64;
  float s=0.f;
#pragma unroll
  for(int d=0;d<64;d++) s = fmaf(q[d],k[d],s);
  out[((size_t)bt*6+h)*502 + j] = s*0.125f;
}

__global__ void fin_pv(const float* __restrict__ p, const float* __restrict__ V1,
                       const float* __restrict__ vseq, float* __restrict__ O){
  int gid = blockIdx.x*256+threadIdx.x;
  if(gid >= 256*384) return;
  int jf = gid % 384; int bt = gid / 384; int b = bt>>1; int h = jf>>6;
  const float* pr = p + ((size_t)bt*6+h)*502;
  float acc=0.f;
  for(int j=0;j<500;j++) acc = fmaf(pr[j], V1[(size_t)j*384+jf], acc);
  acc = fmaf(pr[500], vseq[((size_t)b*2+0)*384+jf], acc);
  acc = fmaf(pr[501], vseq[((size_t)b*2+1)*384+jf], acc);
  O[gid]=acc;
}

__global__ void logits_k(const float* __restrict__ x2, const float* __restrict__ relmem,
                         const float* __restrict__ seqf, float* __restrict__ out){
  int gid = blockIdx.x*256+threadIdx.x;
  if(gid >= 256*502) return;
  int m = gid % 502; int bt = gid / 502; int b = bt>>1;
  const float* x = x2 + (size_t)bt*384;
  const float* mr = (m<500) ? relmem + (size_t)m*384 : seqf + ((size_t)b*2 + (m-500))*384;
  float s=0.f;
#pragma unroll 8
  for(int d=0;d<384;d++) s = fmaf(x[d], mr[d], s);
  out[gid] = s * 0.05103103630798288f;   // 1/sqrt(384)
}

__global__ void pred_copy(const float* __restrict__ logits, float* __restrict__ out){
  int gid = blockIdx.x*256+threadIdx.x;
  if(gid >= 128*502) return;
  int m = gid % 502; int b = gid / 502;
  out[gid] = logits[((size_t)b*2+1)*502 + m];
}

__global__ __launch_bounds__(256)
void final_ent(const float* __restrict__ L2, float* __restrict__ lossBase){
  int row = blockIdx.x;          // 0..255 = b*2+t
  const float* x = L2 + (size_t)row*502;
  int tid = threadIdx.x;
  float m = -1e30f;
  for(int c=tid;c<502;c+=256) m = fmaxf(m, x[c]);
  m = waveMax(m);
  __shared__ float sm[4];
  if((tid&63)==0) sm[tid>>6]=m;
  __syncthreads();
  m = fmaxf(fmaxf(sm[0],sm[1]),fmaxf(sm[2],sm[3]));
  float s=0.f, sx=0.f;
  for(int c=tid;c<502;c+=256){ float e=expf(x[c]-m); s+=e; sx=fmaf(e,x[c],sx); }
  s = waveSum(s); sx = waveSum(sx);
  __shared__ float ps[4], px[4];
  if((tid&63)==0){ ps[tid>>6]=s; px[tid>>6]=sx; }
  __syncthreads();
  if(tid==0){
    float S = ps[0]+ps[1]+ps[2]+ps[3];
    float SX = px[0]+px[1]+px[2]+px[3];
    float ent = (m + logf(S)) - SX/S;
    int b = row>>1, t = row&1;
    lossBase[(size_t)b*9 + 7 + t] = ent;
  }
}

// ---------------- host ----------------
static inline void gemmNT(hipStream_t st, const float* A,int lda,const float* W,int ldw,
                          float* C,int ldc,const float* bias,int M,int N,int K,
                          float scale,int act){
  dim3 g(CDIV(M,64), CDIV(N,64));
  if(act) gemm_nt<1><<<g,256,0,st>>>(A,lda,W,ldw,C,ldc,bias,M,N,K,scale);
  else    gemm_nt<0><<<g,256,0,st>>>(A,lda,W,ldw,C,ldc,bias,M,N,K,scale);
}

extern "C" void kernel_launch(void* const* d_in, const int* in_sizes, int n_in,
                              void* d_out, int out_size, void* d_ws, size_t ws_size,
                              hipStream_t stream){
  (void)in_sizes; (void)n_in; (void)out_size; (void)ws_size;
  const int*   inputs    = (const int*)  d_in[0];
  const float* emb       = (const float*)d_in[1];
  const float* rel_pos   = (const float*)d_in[2];
  const float* qkv_dyn_w = (const float*)d_in[3];
  const float* qkv_dyn_b = (const float*)d_in[4];
  const float* out_dyn_w = (const float*)d_in[5];
  const float* out_dyn_b = (const float*)d_in[6];
  const float* ln_dyn_g  = (const float*)d_in[7];
  const float* ln_dyn_b  = (const float*)d_in[8];
  const float* conv_w    = (const float*)d_in[9];
  const float* conv_b    = (const float*)d_in[10];
  const float* tl_in_w   = (const float*)d_in[11];
  const float* tl_in_b   = (const float*)d_in[12];
  const float* tl_out_w  = (const float*)d_in[13];
  const float* tl_out_b  = (const float*)d_in[14];
  const float* tl_ln1_g  = (const float*)d_in[15];
  const float* tl_ln1_b  = (const float*)d_in[16];
  const float* tl_ln2_g  = (const float*)d_in[17];
  const float* tl_ln2_b  = (const float*)d_in[18];
  const float* tl_ff1_w  = (const float*)d_in[19];
  const float* tl_ff1_b  = (const float*)d_in[20];
  const float* tl_ff2_w  = (const float*)d_in[21];
  const float* tl_ff2_b  = (const float*)d_in[22];
  const float* fc_score_w= (const float*)d_in[23];
  const float* fc_score_b= (const float*)d_in[24];
  const float* fcq_w     = (const float*)d_in[25];
  const float* fcq_b     = (const float*)d_in[26];
  const float* fck_w     = (const float*)d_in[27];
  const float* fck_b     = (const float*)d_in[28];
  const float* fcv_w     = (const float*)d_in[29];
  const float* fcv_b     = (const float*)d_in[30];
  const float* mha_in_w  = (const float*)d_in[31];
  const float* mha_in_b  = (const float*)d_in[32];
  const float* mha_out_w = (const float*)d_in[33];
  const float* mha_out_b = (const float*)d_in[34];
  const float* lnf1_g    = (const float*)d_in[35];
  const float* lnf1_b    = (const float*)d_in[36];
  const float* lnf2_g    = (const float*)d_in[37];
  const float* lnf2_b    = (const float*)d_in[38];
  const float* ff1_w     = (const float*)d_in[39];
  const float* ff1_b     = (const float*)d_in[40];
  const float* ff2_w     = (const float*)d_in[41];
  const float* ff2_b     = (const float*)d_in[42];

  float* ws = (float*)d_ws;
  size_t off = 0;
  auto Aa = [&](size_t n){ float* p = ws + off; off += n; return p; };
  float* relmem = Aa(192000);
  float* KK     = Aa(192000);
  float* VVf    = Aa(192000);
  float* K1mem  = Aa(192000);
  float* V1f    = Aa(192000);
  float* V1l    = Aa(192000);
  float* W0c    = Aa(294912);
  float* W1c    = Aa(294912);
  float* seqA_  = Aa(393216);
  float* seqB_  = Aa(393216);
  float* pairs  = Aa(688128);
  float* xbuf   = Aa(688128);
  float* qkvbuf = Aa(2064384);
  float* obuf   = Aa(688128);
  float* tmpb   = Aa(688128);
  float* ffbuf  = Aa(2752512);
  float* probs2 = Aa(14336);
  float* scbuf  = Aa(896);
  int*   idxb   = (int*)Aa(128);
  float* sel    = Aa(49152);
  float* fq     = Aa(49152);
  float* fq1    = Aa(49152);
  float* fk     = Aa(49152);
  float* fk1    = Aa(49152);
  float* fv     = Aa(49152);
  float* fv1    = Aa(49152);
  float* fo     = Aa(49152);
  float* ftmp   = Aa(49152);
  float* fxf    = Aa(49152);
  float* ffused = Aa(49152);
  float* fffb   = Aa(196608);
  float* fscores= Aa(384768);
  // final-stage aliases (iteration arena is dead by then)
  float* seqf = pairs;
  float* gq   = xbuf;
  float* gq1  = xbuf + 98304;
  float* gk   = xbuf + 196608;
  float* gk1  = xbuf + 294912;
  float* gv1  = xbuf + 393216;
  float* gscores = ffbuf;
  float* gffb = ffbuf + 1048576;
  float* go   = obuf;
  float* gtmp = obuf + 98304;
  float* gx1  = obuf + 196608;
  float* gx2  = obuf + 294912;
  float* logitsb = qkvbuf;

  float* lossBase = (float*)d_out + 128*502;

  // ---------- stage 1: relation_mem ----------
  gemmNT(stream, emb,384, qkv_dyn_w,384, qkvbuf,1152, qkv_dyn_b, 500,1152,384, 1.f,0);
  const float s192 = 0.07216878364870322f;  // 1/sqrt(192)
  for(int h=0;h<2;h++)
    gemmNT(stream, qkvbuf + h*192,1152, qkvbuf + 384 + h*192,1152,
           ffbuf + (size_t)h*250000,500, nullptr, 500,500,192, s192,0);
  softmax_rows<<<1000,256,0,stream>>>(ffbuf, 500);
  for(int h=0;h<2;h++)
    gemm_nn<<<dim3(CDIV(500,64),CDIV(192,64)),256,0,stream>>>(
        ffbuf + (size_t)h*250000,500, qkvbuf + 768 + h*192,1152,
        obuf + h*192,384, 500,192,500, 1.f);
  gemmNT(stream, obuf,384, out_dyn_w,384, tmpb,384, out_dyn_b, 500,384,384, 1.f,0);
  add_ln<<<500,128,0,stream>>>(emb, tmpb, relmem, ln_dyn_g, ln_dyn_b, 500);

  // ---------- batch-invariant K/V projections for fuse/final ----------
  gemmNT(stream, relmem,384, fck_w,384, KK,384, fck_b, 500,384,384, 1.f,0);
  gemmNT(stream, relmem,384, fcv_w,384, VVf,384, fcv_b, 500,384,384, 1.f,0);
  gemmNT(stream, KK,384,  mha_in_w + 384*384,384, K1mem,384, mha_in_b + 384, 500,384,384, 1.f,0);
  gemmNT(stream, VVf,384, mha_in_w + 2*384*384,384, V1f,384, mha_in_b + 768, 500,384,384, 1.f,0);
  gemmNT(stream, KK,384,  mha_in_w + 2*384*384,384, V1l,384, mha_in_b + 768, 500,384,384, 1.f,0);
  prep_conv<<<CDIV(384*384,256),256,0,stream>>>(conv_w, W0c, W1c);
  seq_init<<<CDIV(128*8*384,256),256,0,stream>>>(inputs, emb, rel_pos, seqA_);

  float* seqCur = seqA_; float* seqNxt = seqB_;

  // ---------- merge loop (iterations 0..5; iteration 6 is the Lc==2 skip) ----------
  for(int it=0; it<6; ++it){
    int P = 7 - it;           // pairs per batch = Lc-1
    int N = 128 * P;
    build_pairs<<<CDIV(N*768,256),256,0,stream>>>(seqCur, rel_pos, pairs, N, P);
    // conv1d(k=3,pad=1) over len-2 == two NT gemms against rearranged weights
    gemmNT(stream, pairs,768, W0c,768, xbuf,      768, conv_b, N,384,768, 1.f,0);
    gemmNT(stream, pairs,768, W1c,768, xbuf + 384,768, conv_b, N,384,768, 1.f,0);
    for(int l=0;l<2;l++){
      gemmNT(stream, xbuf,384, tl_in_w + (size_t)l*1152*384,384, qkvbuf,1152,
             tl_in_b + l*1152, 2*N,1152,384, 1.f,0);
      attn2_scores<<<CDIV(N*8,256),256,0,stream>>>(qkvbuf, probs2, N);
      attn2_pv<<<CDIV(N*2*384,256),256,0,stream>>>(qkvbuf, probs2, obuf, N);
      gemmNT(stream, obuf,384, tl_out_w + (size_t)l*384*384,384, tmpb,384,
             tl_out_b + l*384, 2*N,384,384, 1.f,0);
      add_ln<<<2*N,128,0,stream>>>(xbuf, tmpb, xbuf, tl_ln1_g + l*384, tl_ln1_b + l*384, 2*N);
      gemmNT(stream, xbuf,384, tl_ff1_w + (size_t)l*1536*384,384, ffbuf,1536,
             tl_ff1_b + l*1536, 2*N,1536,384, 1.f,1);
      gemmNT(stream, ffbuf,1536, tl_ff2_w + (size_t)l*384*1536,1536, tmpb,384,
             tl_ff2_b + l*384, 2*N,384,1536, 1.f,0);
      add_ln<<<2*N,128,0,stream>>>(xbuf, tmpb, xbuf, tl_ln2_g + l*384, tl_ln2_b + l*384, 2*N);
    }
    score_rows<<<N,64,0,stream>>>(xbuf, fc_score_w, fc_score_b, scbuf, N);
    argmax_ent<<<1,128,0,stream>>>(scbuf, P, idxb, lossBase + it);
    gather_sel<<<CDIV(128*384,256),256,0,stream>>>(xbuf, idxb, sel, P);
    // fuse(sel)
    gemmNT(stream, sel,384, fcq_w,384, fq,384, fcq_b, 128,384,384, 1.f,0);
    gemmNT(stream, fq,384,  mha_in_w,384, fq1,384, mha_in_b, 128,384,384, 1.f,0);
    gemmNT(stream, sel,384, fck_w,384, fk,384, fck_b, 128,384,384, 1.f,0);
    gemmNT(stream, fk,384,  mha_in_w + 384*384,384, fk1,384, mha_in_b + 384, 128,384,384, 1.f,0);
    gemmNT(stream, sel,384, fcv_w,384, fv,384, fcv_b, 128,384,384, 1.f,0);
    gemmNT(stream, fv,384,  mha_in_w + 2*384*384,384, fv1,384, mha_in_b + 768, 128,384,384, 1.f,0);
    fuse_scores<<<CDIV(128*6*501,256),256,0,stream>>>(fq1, K1mem, fk1, fscores);
    softmax_rows<<<768,256,0,stream>>>(fscores, 501);
    fuse_pv<<<CDIV(128*384,256),256,0,stream>>>(fscores, V1f, fv1, fo);
    gemmNT(stream, fo,384, mha_out_w,384, ftmp,384, mha_out_b, 128,384,384, 1.f,0);
    add_ln<<<128,128,0,stream>>>(sel, ftmp, fxf, lnf1_g, lnf1_b, 128);
    gemmNT(stream, fxf,384, ff1_w,384, fffb,1536, ff1_b, 128,1536,384, 1.f,1);
    gemmNT(stream, fffb,1536, ff2_w,1536, ftmp,384, ff2_b, 128,384,1536, 1.f,0);
    add_ln<<<128,128,0,stream>>>(fxf, ftmp, ffused, lnf2_g, lnf2_b, 128);
    merge_seq<<<CDIV(128*P*384,256),256,0,stream>>>(seqCur, ffused, idxb, seqNxt, P);
    float* t_ = seqCur; seqCur = seqNxt; seqNxt = t_;
  }
  zero_loss6<<<1,128,0,stream>>>(lossBase);

  // ---------- final stage (Lf = 2) ----------
  compact_seq<<<CDIV(256*384,256),256,0,stream>>>(seqCur, seqf);
  gemmNT(stream, seqf,384, fcq_w,384, gq,384, fcq_b, 256,384,384, 1.f,0);
  gemmNT(stream, gq,384,   mha_in_w,384, gq1,384, mha_in_b, 256,384,384, 1.f,0);
  gemmNT(stream, seqf,384, fck_w,384, gk,384, fck_b, 256,384,384, 1.f,0);
  gemmNT(stream, gk,384,   mha_in_w + 384*384,384, gk1,384, mha_in_b + 384, 256,384,384, 1.f,0);
  gemmNT(stream, gk,384,   mha_in_w + 2*384*384,384, gv1,384, mha_in_b + 768, 256,384,384, 1.f,0);
  fin_scores<<<CDIV(256*6*502,256),256,0,stream>>>(gq1, K1mem, gk1, gscores);
  softmax_rows<<<1536,256,0,stream>>>(gscores, 502);
  fin_pv<<<CDIV(256*384,256),256,0,stream>>>(gscores, V1l, gv1, go);
  gemmNT(stream, go,384, mha_out_w,384, gtmp,384, mha_out_b, 256,384,384, 1.f,0);
  add_ln<<<256,128,0,stream>>>(seqf, gtmp, gx1, lnf1_g, lnf1_b, 256);
  gemmNT(stream, gx1,384, ff1_w,384, gffb,1536, ff1_b, 256,1536,384, 1.f,1);
  gemmNT(stream, gffb,1536, ff2_w,1536, gtmp,384, ff2_b, 256,384,1536, 1.f,0);
  add_ln<<<256,128,0,stream>>>(gx1, gtmp, gx2, lnf2_g, lnf2_b, 256);
  logits_k<<<CDIV(256*502,256),256,0,stream>>>(gx2, relmem, seqf, logitsb);
  pred_copy<<<CDIV(128*502,256),256,0,stream>>>(logitsb, (float*)d_out);
  final_ent<<<256,256,0,stream>>>(logitsb, lossBase);
}

// Round 2
// 2809.830 us; speedup vs baseline: 2.0306x; 2.0306x over previous
//
#include <hip/hip_runtime.h>

#define CDIV(a,b) (((a)+(b)-1)/(b))

typedef __bf16 bf16x8 __attribute__((ext_vector_type(8)));
typedef float  f32x4  __attribute__((ext_vector_type(4)));
#define MFMA16(a,b,c) __builtin_amdgcn_mfma_f32_16x16x32_bf16(a,b,c,0,0,0)

// ---------------- wave/block reductions ----------------
__device__ __forceinline__ float waveSum(float v){
#pragma unroll
  for(int o=32;o;o>>=1) v += __shfl_xor(v,o);
  return v;
}
__device__ __forceinline__ float waveMax(float v){
#pragma unroll
  for(int o=32;o;o>>=1) v = fmaxf(v,__shfl_xor(v,o));
  return v;
}

// ---------------- bf16 split helpers ----------------
__device__ __forceinline__ unsigned short f2bf(float f){
  unsigned u = __float_as_uint(f);
  u += 0x7FFFu + ((u>>16)&1u);
  return (unsigned short)(u>>16);
}
__device__ __forceinline__ float bf2f(unsigned short h){
  return __uint_as_float(((unsigned)h)<<16);
}
__device__ __forceinline__ void pack8(const float4& x, const float4& y,
                                      uint4& hi, uint4& lo){
  float v[8] = {x.x,x.y,x.z,x.w,y.x,y.y,y.z,y.w};
  unsigned short h[8], l[8];
#pragma unroll
  for(int i=0;i<8;i++){
    h[i] = f2bf(v[i]);
    l[i] = f2bf(v[i] - bf2f(h[i]));
  }
  hi = make_uint4((unsigned)h[0]|((unsigned)h[1]<<16), (unsigned)h[2]|((unsigned)h[3]<<16),
                  (unsigned)h[4]|((unsigned)h[5]<<16), (unsigned)h[6]|((unsigned)h[7]<<16));
  lo = make_uint4((unsigned)l[0]|((unsigned)l[1]<<16), (unsigned)l[2]|((unsigned)l[3]<<16),
                  (unsigned)l[4]|((unsigned)l[5]<<16), (unsigned)l[6]|((unsigned)l[7]<<16));
}

__device__ __forceinline__ bf16x8 ldsfrag(const unsigned short* base, int row, int kb){
  int off = (row<<7) + (kb<<1);
  off ^= (row&7)<<4;
  return *reinterpret_cast<const bf16x8*>(reinterpret_cast<const char*>(base) + off);
}

// ---------------- MFMA bf16x3 NT GEMM ----------------
// C[M,N] = act(A[M,K] @ W[N,K]^T + bias[N]); requires N%64==0, K%64==0.
template<int ACT>
__global__ __launch_bounds__(256)
void gemm3(const float* __restrict__ A, int lda,
           const float* __restrict__ W, int ldw,
           float* __restrict__ C, int ldc,
           const float* __restrict__ bias, int M, int N, int K)
{
  __shared__ unsigned short AsH[64*64];
  __shared__ unsigned short AsL[64*64];
  __shared__ unsigned short WsH[64*64];
  __shared__ unsigned short WsL[64*64];
  const int tid  = threadIdx.x;
  const int bm   = blockIdx.x*64, bn = blockIdx.y*64;
  const int lane = tid & 63, wid = tid >> 6;
  const int wm   = (wid&1)*32, wn = (wid>>1)*32;
  const int r0   = tid>>3;          // staging slot0 row (0..31)
  const int kq   = (tid&7)*8;       // staging k offset

  float4 gA[2][2], gW[2][2];
  auto loadG = [&](int k0){
#pragma unroll
    for(int i=0;i<2;i++){
      int r = r0 + i*32;
      if(bm+r < M){
        const float* pa = A + (size_t)(bm+r)*lda + k0 + kq;
        gA[i][0] = *reinterpret_cast<const float4*>(pa);
        gA[i][1] = *reinterpret_cast<const float4*>(pa+4);
      } else {
        gA[i][0] = make_float4(0.f,0.f,0.f,0.f);
        gA[i][1] = make_float4(0.f,0.f,0.f,0.f);
      }
      const float* pw = W + (size_t)(bn+r)*ldw + k0 + kq;
      gW[i][0] = *reinterpret_cast<const float4*>(pw);
      gW[i][1] = *reinterpret_cast<const float4*>(pw+4);
    }
  };
  auto writeL = [&](){
#pragma unroll
    for(int i=0;i<2;i++){
      int r = r0 + i*32;
      int off = (r<<7) + (tid&7)*16;
      off ^= (r&7)<<4;
      uint4 hi, lo;
      pack8(gA[i][0], gA[i][1], hi, lo);
      *reinterpret_cast<uint4*>(reinterpret_cast<char*>(AsH) + off) = hi;
      *reinterpret_cast<uint4*>(reinterpret_cast<char*>(AsL) + off) = lo;
      pack8(gW[i][0], gW[i][1], hi, lo);
      *reinterpret_cast<uint4*>(reinterpret_cast<char*>(WsH) + off) = hi;
      *reinterpret_cast<uint4*>(reinterpret_cast<char*>(WsL) + off) = lo;
    }
  };

  f32x4 acc[2][2];
#pragma unroll
  for(int mi=0;mi<2;mi++)
#pragma unroll
    for(int ni=0;ni<2;ni++) acc[mi][ni] = f32x4{0.f,0.f,0.f,0.f};

  loadG(0);
  for(int k0=0; k0<K; k0+=64){
    __syncthreads();
    writeL();
    __syncthreads();
    if(k0+64 < K) loadG(k0+64);
    const int lk = (lane>>4)*8;
    const int lc = lane&15;
#pragma unroll
    for(int kk=0; kk<2; kk++){
      int kb = kk*32 + lk;
      bf16x8 aH[2], aL[2], bH[2], bL[2];
#pragma unroll
      for(int m=0;m<2;m++){
        aH[m] = ldsfrag(AsH, wm + lc + m*16, kb);
        aL[m] = ldsfrag(AsL, wm + lc + m*16, kb);
        bH[m] = ldsfrag(WsH, wn + lc + m*16, kb);
        bL[m] = ldsfrag(WsL, wn + lc + m*16, kb);
      }
#pragma unroll
      for(int mi=0;mi<2;mi++)
#pragma unroll
        for(int ni=0;ni<2;ni++){
          acc[mi][ni] = MFMA16(aH[mi], bH[ni], acc[mi][ni]);
          acc[mi][ni] = MFMA16(aH[mi], bL[ni], acc[mi][ni]);
          acc[mi][ni] = MFMA16(aL[mi], bH[ni], acc[mi][ni]);
        }
    }
  }

  const int lr = lane>>4, lc = lane&15;
#pragma unroll
  for(int mi=0;mi<2;mi++)
#pragma unroll
    for(int ni=0;ni<2;ni++)
#pragma unroll
      for(int r=0;r<4;r++){
        int row = bm + wm + mi*16 + lr*4 + r;
        if(row>=M) continue;
        int col = bn + wn + ni*16 + lc;
        float v = acc[mi][ni][r] + (bias ? bias[col] : 0.f);
        if(ACT==1) v = 0.5f*v*(1.f+erff(v*0.70710678118654752f));
        C[(size_t)row*ldc+col] = v;
      }
}

// ---------------- f32 tiled GEMMs (irregular shapes only) ----------------
template<int ACT>
__global__ __launch_bounds__(256)
void gemm_nt(const float* __restrict__ A, int lda,
             const float* __restrict__ W, int ldw,
             float* __restrict__ C, int ldc,
             const float* __restrict__ bias,
             int M, int N, int K, float scale)
{
  __shared__ float As[16][68];
  __shared__ float Ws[16][68];
  const int bm = blockIdx.x*64, bn = blockIdx.y*64;
  const int tid = threadIdx.x;
  const int lr = tid>>2;
  const int kq = (tid&3)<<2;
  const int tx = tid&15, ty = tid>>4;
  float acc[4][4] = {};
  for(int k0=0;k0<K;k0+=16){
    float4 av = make_float4(0.f,0.f,0.f,0.f), wv = make_float4(0.f,0.f,0.f,0.f);
    if(bm+lr < M && k0+kq < K) av = *reinterpret_cast<const float4*>(A + (size_t)(bm+lr)*lda + k0+kq);
    if(bn+lr < N && k0+kq < K) wv = *reinterpret_cast<const float4*>(W + (size_t)(bn+lr)*ldw + k0+kq);
    As[kq+0][lr]=av.x; As[kq+1][lr]=av.y; As[kq+2][lr]=av.z; As[kq+3][lr]=av.w;
    Ws[kq+0][lr]=wv.x; Ws[kq+1][lr]=wv.y; Ws[kq+2][lr]=wv.z; Ws[kq+3][lr]=wv.w;
    __syncthreads();
#pragma unroll
    for(int k=0;k<16;k++){
      float4 a4 = *reinterpret_cast<const float4*>(&As[k][ty<<2]);
      float4 w4 = *reinterpret_cast<const float4*>(&Ws[k][tx<<2]);
      float aa[4]={a4.x,a4.y,a4.z,a4.w};
      float ww[4]={w4.x,w4.y,w4.z,w4.w};
#pragma unroll
      for(int i=0;i<4;i++)
#pragma unroll
        for(int j=0;j<4;j++) acc[i][j] = fmaf(aa[i],ww[j],acc[i][j]);
    }
    __syncthreads();
  }
#pragma unroll
  for(int i=0;i<4;i++){
    int row = bm + (ty<<2) + i;
    if(row>=M) continue;
#pragma unroll
    for(int j=0;j<4;j++){
      int col = bn + (tx<<2) + j;
      if(col>=N) continue;
      float v = acc[i][j]*scale + (bias? bias[col] : 0.f);
      if(ACT==1) v = 0.5f*v*(1.f+erff(v*0.70710678118654752f));
      C[(size_t)row*ldc+col]=v;
    }
  }
}

__global__ __launch_bounds__(256)
void gemm_nn(const float* __restrict__ A, int lda,
             const float* __restrict__ Bm, int ldb,
             float* __restrict__ C, int ldc,
             int M, int N, int K, float scale)
{
  __shared__ float As[16][68];
  __shared__ float Bs[16][68];
  const int bm = blockIdx.x*64, bn = blockIdx.y*64;
  const int tid = threadIdx.x;
  const int lr = tid>>2;
  const int kq = (tid&3)<<2;
  const int kr = tid>>4;
  const int nq = (tid&15)<<2;
  const int tx = tid&15, ty = tid>>4;
  float acc[4][4] = {};
  for(int k0=0;k0<K;k0+=16){
    float4 av = make_float4(0.f,0.f,0.f,0.f), bv = make_float4(0.f,0.f,0.f,0.f);
    if(bm+lr < M && k0+kq < K) av = *reinterpret_cast<const float4*>(A + (size_t)(bm+lr)*lda + k0+kq);
    if(k0+kr < K && bn+nq < N) bv = *reinterpret_cast<const float4*>(Bm + (size_t)(k0+kr)*ldb + bn+nq);
    As[kq+0][lr]=av.x; As[kq+1][lr]=av.y; As[kq+2][lr]=av.z; As[kq+3][lr]=av.w;
    Bs[kr][nq+0]=bv.x; Bs[kr][nq+1]=bv.y; Bs[kr][nq+2]=bv.z; Bs[kr][nq+3]=bv.w;
    __syncthreads();
#pragma unroll
    for(int k=0;k<16;k++){
      float4 a4 = *reinterpret_cast<const float4*>(&As[k][ty<<2]);
      float4 b4 = *reinterpret_cast<const float4*>(&Bs[k][tx<<2]);
      float aa[4]={a4.x,a4.y,a4.z,a4.w};
      float bb[4]={b4.x,b4.y,b4.z,b4.w};
#pragma unroll
      for(int i=0;i<4;i++)
#pragma unroll
        for(int j=0;j<4;j++) acc[i][j] = fmaf(aa[i],bb[j],acc[i][j]);
    }
    __syncthreads();
  }
#pragma unroll
  for(int i=0;i<4;i++){
    int row = bm + (ty<<2) + i;
    if(row>=M) continue;
#pragma unroll
    for(int j=0;j<4;j++){
      int col = bn + (tx<<2) + j;
      if(col>=N) continue;
      C[(size_t)row*ldc+col]=acc[i][j]*scale;
    }
  }
}

// ---------------- LayerNorm(x + t) over 384, row-per-block (128 thr) ----------------
__global__ __launch_bounds__(128)
void add_ln(const float* __restrict__ X, const float* __restrict__ T,
            float* __restrict__ O, const float* __restrict__ g,
            const float* __restrict__ be, int M)
{
  int row = blockIdx.x;
  if(row>=M) return;
  const float* x = X + (size_t)row*384;
  const float* t = T + (size_t)row*384;
  float* o = O + (size_t)row*384;
  int tid = threadIdx.x;
  float v[3]; float s=0.f;
#pragma unroll
  for(int i=0;i<3;i++){ int c = tid + i*128; v[i] = x[c] + t[c]; s += v[i]; }
  s = waveSum(s);
  __shared__ float p1[2];
  if((tid&63)==0) p1[tid>>6]=s;
  __syncthreads();
  float mean = (p1[0]+p1[1])*(1.f/384.f);
  float vs=0.f;
#pragma unroll
  for(int i=0;i<3;i++){ float d=v[i]-mean; vs += d*d; }
  vs = waveSum(vs);
  __shared__ float p2[2];
  if((tid&63)==0) p2[tid>>6]=vs;
  __syncthreads();
  float rstd = rsqrtf((p2[0]+p2[1])*(1.f/384.f) + 1e-5f);
#pragma unroll
  for(int i=0;i<3;i++){ int c = tid + i*128; o[c] = (v[i]-mean)*rstd*g[c] + be[c]; }
}

// ---------------- generic row softmax (in place) ----------------
__global__ __launch_bounds__(256)
void softmax_rows(float* __restrict__ X, int cols)
{
  float* x = X + (size_t)blockIdx.x*cols;
  int tid = threadIdx.x;
  float m = -1e30f;
  for(int c=tid;c<cols;c+=256) m = fmaxf(m, x[c]);
  m = waveMax(m);
  __shared__ float sm[4];
  if((tid&63)==0) sm[tid>>6]=m;
  __syncthreads();
  m = fmaxf(fmaxf(sm[0],sm[1]),fmaxf(sm[2],sm[3]));
  float s=0.f;
  for(int c=tid;c<cols;c+=256){ float e = expf(x[c]-m); x[c]=e; s+=e; }
  s = waveSum(s);
  __shared__ float ss[4];
  if((tid&63)==0) ss[tid>>6]=s;
  __syncthreads();
  s = ss[0]+ss[1]+ss[2]+ss[3];
  float inv = 1.f/s;
  for(int c=tid;c<cols;c+=256) x[c]*=inv;
}

// ---------------- misc small kernels ----------------
__global__ void prep_conv(const float* __restrict__ cw, float* __restrict__ W0, float* __restrict__ W1){
  int gid = blockIdx.x*256+threadIdx.x;
  if(gid >= 384*384) return;
  int i = gid % 384, o = gid / 384;
  const float* w = cw + (size_t)gid*3;
  W0[(size_t)o*768 + i]       = w[1];
  W0[(size_t)o*768 + 384 + i] = w[2];
  W1[(size_t)o*768 + i]       = w[0];
  W1[(size_t)o*768 + 384 + i] = w[1];
}

__global__ void seq_init(const int* __restrict__ inp, const float* __restrict__ emb,
                         const float* __restrict__ rp, float* __restrict__ seq){
  int gid = blockIdx.x*256+threadIdx.x;
  if(gid >= 128*8*384) return;
  int j = gid % 384; int l = (gid/384) & 7; int b = gid / 3072;
  int tok = inp[b*8 + l];
  seq[gid] = emb[(size_t)tok*384 + j] + rp[l*384 + j];
}

__global__ void build_pairs(const float* __restrict__ seq, const float* __restrict__ rp,
                            float* __restrict__ pairs, int N, int P){
  int gid = blockIdx.x*256+threadIdx.x;
  if(gid >= N*768) return;
  int c = gid % 768; int n = gid / 768;
  int t = c / 384; int j = c % 384;
  int i = n % P; int b = n / P;
  pairs[gid] = seq[((size_t)b*8 + i + t)*384 + j] + rp[t*384 + j];
}

__global__ void attn2_scores(const float* __restrict__ QKV, float* __restrict__ probs, int N){
  int gid = blockIdx.x*256 + threadIdx.x;
  if(gid >= N*8) return;
  int t = gid & 1; int h = (gid>>1) & 3; int n = gid>>3;
  const float* q  = QKV + ((size_t)(n*2+t))*1152 + h*96;
  const float* k0 = QKV + ((size_t)(n*2+0))*1152 + 384 + h*96;
  const float* k1 = k0 + 1152;
  float s0=0.f, s1=0.f;
#pragma unroll 8
  for(int d=0;d<96;d++){ float qd=q[d]; s0=fmaf(qd,k0[d],s0); s1=fmaf(qd,k1[d],s1); }
  const float sc = 0.1020620726159658f;
  s0*=sc; s1*=sc;
  float m=fmaxf(s0,s1);
  float e0=expf(s0-m), e1=expf(s1-m);
  float inv=1.f/(e0+e1);
  float* p = probs + (size_t)gid*2;
  p[0]=e0*inv; p[1]=e1*inv;
}

__global__ void attn2_pv(const float* __restrict__ QKV, const float* __restrict__ probs,
                         float* __restrict__ O, int N){
  int gid = blockIdx.x*256 + threadIdx.x;
  if(gid >= N*2*384) return;
  int j = gid % 384; int r = gid / 384;
  int n = r >> 1, t = r & 1; int h = j / 96;
  const float* p = probs + (((size_t)n*4+h)*2+t)*2;
  float v0 = QKV[(size_t)(n*2+0)*1152 + 768 + j];
  float v1 = QKV[(size_t)(n*2+1)*1152 + 768 + j];
  O[gid] = p[0]*v0 + p[1]*v1;
}

__global__ __launch_bounds__(64)
void score_rows(const float* __restrict__ X, const float* __restrict__ w,
                const float* __restrict__ b0, float* __restrict__ sc, int N){
  int n = blockIdx.x;
  if(n>=N) return;
  const float* x = X + ((size_t)n*2+1)*384;
  int tid = threadIdx.x;
  float s=0.f;
#pragma unroll
  for(int i=0;i<6;i++){ int c = tid + i*64; s = fmaf(x[c], w[c], s); }
  s = waveSum(s);
  if(tid==0) sc[n] = 1.f/(1.f+expf(-(s + b0[0])));
}

__global__ void argmax_ent(const float* __restrict__ sc, int P, int* __restrict__ idx,
                           float* __restrict__ loss_slot){
  int b = threadIdx.x;
  if(b>=128) return;
  const float* s = sc + (size_t)b*P;
  float m = s[0]; int am = 0;
  for(int i=1;i<P;i++){ float v=s[i]; if(v>m){m=v;am=i;} }
  float z=0.f, sx=0.f;
  for(int i=0;i<P;i++){ float e=expf(s[i]-m); z+=e; sx=fmaf(e,s[i],sx); }
  float logZ = m + logf(z);
  idx[b]=am;
  loss_slot[(size_t)b*9] = logZ - sx/z;
}

__global__ void gather_sel(const float* __restrict__ X, const int* __restrict__ idx,
                           float* __restrict__ sel, int P){
  int gid = blockIdx.x*256+threadIdx.x;
  if(gid >= 128*384) return;
  int j = gid % 384; int b = gid / 384;
  sel[gid] = X[(((size_t)b*P + idx[b])*2 + 1)*384 + j];
}

__global__ void fuse_scores(const float* __restrict__ q1, const float* __restrict__ K1,
                            const float* __restrict__ ksel, float* __restrict__ out){
  int gid = blockIdx.x*256+threadIdx.x;
  if(gid >= 128*6*501) return;
  int j = gid % 501; int bh = gid / 501; int h = bh % 6; int b = bh / 6;
  const float* q = q1 + (size_t)b*384 + h*64;
  const float* k = (j<500) ? K1 + (size_t)j*384 + h*64 : ksel + (size_t)b*384 + h*64;
  float s=0.f;
#pragma unroll
  for(int d=0;d<64;d++) s = fmaf(q[d],k[d],s);
  out[(size_t)bh*501 + j] = s*0.125f;
}

__global__ void fuse_pv(const float* __restrict__ p, const float* __restrict__ V1,
                        const float* __restrict__ vsel, float* __restrict__ O){
  int gid = blockIdx.x*256+threadIdx.x;
  if(gid >= 128*384) return;
  int jf = gid % 384; int b = gid / 384; int h = jf >> 6;
  const float* pr = p + ((size_t)b*6+h)*501;
  float acc=0.f;
  for(int j=0;j<500;j++) acc = fmaf(pr[j], V1[(size_t)j*384+jf], acc);
  acc = fmaf(pr[500], vsel[(size_t)b*384+jf], acc);
  O[gid]=acc;
}

__global__ void merge_seq(const float* __restrict__ src, const float* __restrict__ fused,
                          const int* __restrict__ idx, float* __restrict__ dst, int P){
  int gid = blockIdx.x*256+threadIdx.x;
  if(gid >= 128*P*384) return;
  int j = gid % 384; int rest = gid / 384; int i = rest % P; int b = rest / P;
  int id = idx[b];
  float v;
  if(i == id) v = fused[(size_t)b*384 + j];
  else        v = src[((size_t)b*8 + i + (i>id ? 1:0))*384 + j];
  dst[((size_t)b*8 + i)*384 + j] = v;
}

__global__ void zero_loss6(float* __restrict__ lossBase){
  int b = threadIdx.x;
  if(b<128) lossBase[(size_t)b*9 + 6] = 0.f;
}

__global__ void compact_seq(const float* __restrict__ seq, float* __restrict__ out){
  int gid = blockIdx.x*256+threadIdx.x;
  if(gid >= 256*384) return;
  int j = gid % 384; int r = gid / 384; int b = r>>1; int t = r&1;
  out[gid] = seq[((size_t)b*8 + t)*384 + j];
}

__global__ void fin_scores(const float* __restrict__ q1, const float* __restrict__ K1,
                           const float* __restrict__ kseq, float* __restrict__ out){
  int gid = blockIdx.x*256+threadIdx.x;
  if(gid >= 256*6*502) return;
  int j = gid % 502; int bth = gid / 502; int h = bth % 6; int bt = bth / 6;
  int b = bt >> 1;
  const float* q = q1 + (size_t)bt*384 + h*64;
  const float* k = (j<500) ? K1 + (size_t)j*384 + h*64
                           : kseq + ((size_t)b*2 + (j-500))*384 + h*64;
  float s=0.f;
#pragma unroll
  for(int d=0;d<64;d++) s = fmaf(q[d],k[d],s);
  out[((size_t)bt*6+h)*502 + j] = s*0.125f;
}

__global__ void fin_pv(const float* __restrict__ p, const float* __restrict__ V1,
                       const float* __restrict__ vseq, float* __restrict__ O){
  int gid = blockIdx.x*256+threadIdx.x;
  if(gid >= 256*384) return;
  int jf = gid % 384; int bt = gid / 384; int b = bt>>1; int h = jf>>6;
  const float* pr = p + ((size_t)bt*6+h)*502;
  float acc=0.f;
  for(int j=0;j<500;j++) acc = fmaf(pr[j], V1[(size_t)j*384+jf], acc);
  acc = fmaf(pr[500], vseq[((size_t)b*2+0)*384+jf], acc);
  acc = fmaf(pr[501], vseq[((size_t)b*2+1)*384+jf], acc);
  O[gid]=acc;
}

__global__ void logits_k(const float* __restrict__ x2, const float* __restrict__ relmem,
                         const float* __restrict__ seqf, float* __restrict__ out){
  int gid = blockIdx.x*256+threadIdx.x;
  if(gid >= 256*502) return;
  int m = gid % 502; int bt = gid / 502; int b = bt>>1;
  const float* x = x2 + (size_t)bt*384;
  const float* mr = (m<500) ? relmem + (size_t)m*384 : seqf + ((size_t)b*2 + (m-500))*384;
  float s=0.f;
#pragma unroll 8
  for(int d=0;d<384;d++) s = fmaf(x[d], mr[d], s);
  out[gid] = s * 0.05103103630798288f;
}

__global__ void pred_copy(const float* __restrict__ logits, float* __restrict__ out){
  int gid = blockIdx.x*256+threadIdx.x;
  if(gid >= 128*502) return;
  int m = gid % 502; int b = gid / 502;
  out[gid] = logits[((size_t)b*2+1)*502 + m];
}

__global__ __launch_bounds__(256)
void final_ent(const float* __restrict__ L2, float* __restrict__ lossBase){
  int row = blockIdx.x;
  const float* x = L2 + (size_t)row*502;
  int tid = threadIdx.x;
  float m = -1e30f;
  for(int c=tid;c<502;c+=256) m = fmaxf(m, x[c]);
  m = waveMax(m);
  __shared__ float sm[4];
  if((tid&63)==0) sm[tid>>6]=m;
  __syncthreads();
  m = fmaxf(fmaxf(sm[0],sm[1]),fmaxf(sm[2],sm[3]));
  float s=0.f, sx=0.f;
  for(int c=tid;c<502;c+=256){ float e=expf(x[c]-m); s+=e; sx=fmaf(e,x[c],sx); }
  s = waveSum(s); sx = waveSum(sx);
  __shared__ float ps[4], px[4];
  if((tid&63)==0){ ps[tid>>6]=s; px[tid>>6]=sx; }
  __syncthreads();
  if(tid==0){
    float S = ps[0]+ps[1]+ps[2]+ps[3];
    float SX = px[0]+px[1]+px[2]+px[3];
    float ent = (m + logf(S)) - SX/S;
    int b = row>>1, t = row&1;
    lossBase[(size_t)b*9 + 7 + t] = ent;
  }
}

// ---------------- host ----------------
static inline void gemmNT(hipStream_t st, const float* A,int lda,const float* W,int ldw,
                          float* C,int ldc,const float* bias,int M,int N,int K,
                          float scale,int act){
  if(scale==1.f && (N&63)==0 && (K&63)==0){
    dim3 g(CDIV(M,64), N/64);
    if(act) gemm3<1><<<g,256,0,st>>>(A,lda,W,ldw,C,ldc,bias,M,N,K);
    else    gemm3<0><<<g,256,0,st>>>(A,lda,W,ldw,C,ldc,bias,M,N,K);
  } else {
    dim3 g(CDIV(M,64), CDIV(N,64));
    if(act) gemm_nt<1><<<g,256,0,st>>>(A,lda,W,ldw,C,ldc,bias,M,N,K,scale);
    else    gemm_nt<0><<<g,256,0,st>>>(A,lda,W,ldw,C,ldc,bias,M,N,K,scale);
  }
}

extern "C" void kernel_launch(void* const* d_in, const int* in_sizes, int n_in,
                              void* d_out, int out_size, void* d_ws, size_t ws_size,
                              hipStream_t stream){
  (void)in_sizes; (void)n_in; (void)out_size; (void)ws_size;
  const int*   inputs    = (const int*)  d_in[0];
  const float* emb       = (const float*)d_in[1];
  const float* rel_pos   = (const float*)d_in[2];
  const float* qkv_dyn_w = (const float*)d_in[3];
  const float* qkv_dyn_b = (const float*)d_in[4];
  const float* out_dyn_w = (const float*)d_in[5];
  const float* out_dyn_b = (const float*)d_in[6];
  const float* ln_dyn_g  = (const float*)d_in[7];
  const float* ln_dyn_b  = (const float*)d_in[8];
  const float* conv_w    = (const float*)d_in[9];
  const float* conv_b    = (const float*)d_in[10];
  const float* tl_in_w   = (const float*)d_in[11];
  const float* tl_in_b   = (const float*)d_in[12];
  const float* tl_out_w  = (const float*)d_in[13];
  const float* tl_out_b  = (const float*)d_in[14];
  const float* tl_ln1_g  = (const float*)d_in[15];
  const float* tl_ln1_b  = (const float*)d_in[16];
  const float* tl_ln2_g  = (const float*)d_in[17];
  const float* tl_ln2_b  = (const float*)d_in[18];
  const float* tl_ff1_w  = (const float*)d_in[19];
  const float* tl_ff1_b  = (const float*)d_in[20];
  const float* tl_ff2_w  = (const float*)d_in[21];
  const float* tl_ff2_b  = (const float*)d_in[22];
  const float* fc_score_w= (const float*)d_in[23];
  const float* fc_score_b= (const float*)d_in[24];
  const float* fcq_w     = (const float*)d_in[25];
  const float* fcq_b     = (const float*)d_in[26];
  const float* fck_w     = (const float*)d_in[27];
  const float* fck_b     = (const float*)d_in[28];
  const float* fcv_w     = (const float*)d_in[29];
  const float* fcv_b     = (const float*)d_in[30];
  const float* mha_in_w  = (const float*)d_in[31];
  const float* mha_in_b  = (const float*)d_in[32];
  const float* mha_out_w = (const float*)d_in[33];
  const float* mha_out_b = (const float*)d_in[34];
  const float* lnf1_g    = (const float*)d_in[35];
  const float* lnf1_b    = (const float*)d_in[36];
  const float* lnf2_g    = (const float*)d_in[37];
  const float* lnf2_b    = (const float*)d_in[38];
  const float* ff1_w     = (const float*)d_in[39];
  const float* ff1_b     = (const float*)d_in[40];
  const float* ff2_w     = (const float*)d_in[41];
  const float* ff2_b     = (const float*)d_in[42];

  float* ws = (float*)d_ws;
  size_t off = 0;
  auto Aa = [&](size_t n){ float* p = ws + off; off += n; return p; };
  float* relmem = Aa(192000);
  float* KK     = Aa(192000);
  float* VVf    = Aa(192000);
  float* K1mem  = Aa(192000);
  float* V1f    = Aa(192000);
  float* V1l    = Aa(192000);
  float* W0c    = Aa(294912);
  float* W1c    = Aa(294912);
  float* seqA_  = Aa(393216);
  float* seqB_  = Aa(393216);
  float* pairs  = Aa(688128);
  float* xbuf   = Aa(688128);
  float* qkvbuf = Aa(2064384);
  float* obuf   = Aa(688128);
  float* tmpb   = Aa(688128);
  float* ffbuf  = Aa(2752512);
  float* probs2 = Aa(14336);
  float* scbuf  = Aa(896);
  int*   idxb   = (int*)Aa(128);
  float* sel    = Aa(49152);
  float* fq     = Aa(49152);
  float* fq1    = Aa(49152);
  float* fk     = Aa(49152);
  float* fk1    = Aa(49152);
  float* fv     = Aa(49152);
  float* fv1    = Aa(49152);
  float* fo     = Aa(49152);
  float* ftmp   = Aa(49152);
  float* fxf    = Aa(49152);
  float* ffused = Aa(49152);
  float* fffb   = Aa(196608);
  float* fscores= Aa(384768);
  float* seqf = pairs;
  float* gq   = xbuf;
  float* gq1  = xbuf + 98304;
  float* gk   = xbuf + 196608;
  float* gk1  = xbuf + 294912;
  float* gv1  = xbuf + 393216;
  float* gscores = ffbuf;
  float* gffb = ffbuf + 1048576;
  float* go   = obuf;
  float* gtmp = obuf + 98304;
  float* gx1  = obuf + 196608;
  float* gx2  = obuf + 294912;
  float* logitsb = qkvbuf;

  float* lossBase = (float*)d_out + 128*502;

  // ---------- stage 1: relation_mem ----------
  gemmNT(stream, emb,384, qkv_dyn_w,384, qkvbuf,1152, qkv_dyn_b, 500,1152,384, 1.f,0);
  const float s192 = 0.07216878364870322f;
  for(int h=0;h<2;h++)
    gemmNT(stream, qkvbuf + h*192,1152, qkvbuf + 384 + h*192,1152,
           ffbuf + (size_t)h*250000,500, nullptr, 500,500,192, s192,0);
  softmax_rows<<<1000,256,0,stream>>>(ffbuf, 500);
  for(int h=0;h<2;h++)
    gemm_nn<<<dim3(CDIV(500,64),CDIV(192,64)),256,0,stream>>>(
        ffbuf + (size_t)h*250000,500, qkvbuf + 768 + h*192,1152,
        obuf + h*192,384, 500,192,500, 1.f);
  gemmNT(stream, obuf,384, out_dyn_w,384, tmpb,384, out_dyn_b, 500,384,384, 1.f,0);
  add_ln<<<500,128,0,stream>>>(emb, tmpb, relmem, ln_dyn_g, ln_dyn_b, 500);

  // ---------- batch-invariant K/V projections for fuse/final ----------
  gemmNT(stream, relmem,384, fck_w,384, KK,384, fck_b, 500,384,384, 1.f,0);
  gemmNT(stream, relmem,384, fcv_w,384, VVf,384, fcv_b, 500,384,384, 1.f,0);
  gemmNT(stream, KK,384,  mha_in_w + 384*384,384, K1mem,384, mha_in_b + 384, 500,384,384, 1.f,0);
  gemmNT(stream, VVf,384, mha_in_w + 2*384*384,384, V1f,384, mha_in_b + 768, 500,384,384, 1.f,0);
  gemmNT(stream, KK,384,  mha_in_w + 2*384*384,384, V1l,384, mha_in_b + 768, 500,384,384, 1.f,0);
  prep_conv<<<CDIV(384*384,256),256,0,stream>>>(conv_w, W0c, W1c);
  seq_init<<<CDIV(128*8*384,256),256,0,stream>>>(inputs, emb, rel_pos, seqA_);

  float* seqCur = seqA_; float* seqNxt = seqB_;

  // ---------- merge loop ----------
  for(int it=0; it<6; ++it){
    int P = 7 - it;
    int N = 128 * P;
    build_pairs<<<CDIV(N*768,256),256,0,stream>>>(seqCur, rel_pos, pairs, N, P);
    gemmNT(stream, pairs,768, W0c,768, xbuf,      768, conv_b, N,384,768, 1.f,0);
    gemmNT(stream, pairs,768, W1c,768, xbuf + 384,768, conv_b, N,384,768, 1.f,0);
    for(int l=0;l<2;l++){
      gemmNT(stream, xbuf,384, tl_in_w + (size_t)l*1152*384,384, qkvbuf,1152,
             tl_in_b + l*1152, 2*N,1152,384, 1.f,0);
      attn2_scores<<<CDIV(N*8,256),256,0,stream>>>(qkvbuf, probs2, N);
      attn2_pv<<<CDIV(N*2*384,256),256,0,stream>>>(qkvbuf, probs2, obuf, N);
      gemmNT(stream, obuf,384, tl_out_w + (size_t)l*384*384,384, tmpb,384,
             tl_out_b + l*384, 2*N,384,384, 1.f,0);
      add_ln<<<2*N,128,0,stream>>>(xbuf, tmpb, xbuf, tl_ln1_g + l*384, tl_ln1_b + l*384, 2*N);
      gemmNT(stream, xbuf,384, tl_ff1_w + (size_t)l*1536*384,384, ffbuf,1536,
             tl_ff1_b + l*1536, 2*N,1536,384, 1.f,1);
      gemmNT(stream, ffbuf,1536, tl_ff2_w + (size_t)l*384*1536,1536, tmpb,384,
             tl_ff2_b + l*384, 2*N,384,1536, 1.f,0);
      add_ln<<<2*N,128,0,stream>>>(xbuf, tmpb, xbuf, tl_ln2_g + l*384, tl_ln2_b + l*384, 2*N);
    }
    score_rows<<<N,64,0,stream>>>(xbuf, fc_score_w, fc_score_b, scbuf, N);
    argmax_ent<<<1,128,0,stream>>>(scbuf, P, idxb, lossBase + it);
    gather_sel<<<CDIV(128*384,256),256,0,stream>>>(xbuf, idxb, sel, P);
    gemmNT(stream, sel,384, fcq_w,384, fq,384, fcq_b, 128,384,384, 1.f,0);
    gemmNT(stream, fq,384,  mha_in_w,384, fq1,384, mha_in_b, 128,384,384, 1.f,0);
    gemmNT(stream, sel,384, fck_w,384, fk,384, fck_b, 128,384,384, 1.f,0);
    gemmNT(stream, fk,384,  mha_in_w + 384*384,384, fk1,384, mha_in_b + 384, 128,384,384, 1.f,0);
    gemmNT(stream, sel,384, fcv_w,384, fv,384, fcv_b, 128,384,384, 1.f,0);
    gemmNT(stream, fv,384,  mha_in_w + 2*384*384,384, fv1,384, mha_in_b + 768, 128,384,384, 1.f,0);
    fuse_scores<<<CDIV(128*6*501,256),256,0,stream>>>(fq1, K1mem, fk1, fscores);
    softmax_rows<<<768,256,0,stream>>>(fscores, 501);
    fuse_pv<<<CDIV(128*384,256),256,0,stream>>>(fscores, V1f, fv1, fo);
    gemmNT(stream, fo,384, mha_out_w,384, ftmp,384, mha_out_b, 128,384,384, 1.f,0);
    add_ln<<<128,128,0,stream>>>(sel, ftmp, fxf, lnf1_g, lnf1_b, 128);
    gemmNT(stream, fxf,384, ff1_w,384, fffb,1536, ff1_b, 128,1536,384, 1.f,1);
    gemmNT(stream, fffb,1536, ff2_w,1536, ftmp,384, ff2_b, 128,384,1536, 1.f,0);
    add_ln<<<128,128,0,stream>>>(fxf, ftmp, ffused, lnf2_g, lnf2_b, 128);
    merge_seq<<<CDIV(128*P*384,256),256,0,stream>>>(seqCur, ffused, idxb, seqNxt, P);
    float* t_ = seqCur; seqCur = seqNxt; seqNxt = t_;
  }
  zero_loss6<<<1,128,0,stream>>>(lossBase);

  // ---------- final stage ----------
  compact_seq<<<CDIV(256*384,256),256,0,stream>>>(seqCur, seqf);
  gemmNT(stream, seqf,384, fcq_w,384, gq,384, fcq_b, 256,384,384, 1.f,0);
  gemmNT(stream, gq,384,   mha_in_w,384, gq1,384, mha_in_b, 256,384,384, 1.f,0);
  gemmNT(stream, seqf,384, fck_w,384, gk,384, fck_b, 256,384,384, 1.f,0);
  gemmNT(stream, gk,384,   mha_in_w + 384*384,384, gk1,384, mha_in_b + 384, 256,384,384, 1.f,0);
  gemmNT(stream, gk,384,   mha_in_w + 2*384*384,384, gv1,384, mha_in_b + 768, 256,384,384, 1.f,0);
  fin_scores<<<CDIV(256*6*502,256),256,0,stream>>>(gq1, K1mem, gk1, gscores);
  softmax_rows<<<1536,256,0,stream>>>(gscores, 502);
  fin_pv<<<CDIV(256*384,256),256,0,stream>>>(gscores, V1l, gv1, go);
  gemmNT(stream, go,384, mha_out_w,384, gtmp,384, mha_out_b, 256,384,384, 1.f,0);
  add_ln<<<256,128,0,stream>>>(seqf, gtmp, gx1, lnf1_g, lnf1_b, 256);
  gemmNT(stream, gx1,384, ff1_w,384, gffb,1536, ff1_b, 256,1536,384, 1.f,1);
  gemmNT(stream, gffb,1536, ff2_w,1536, gtmp,384, ff2_b, 256,384,1536, 1.f,0);
  add_ln<<<256,128,0,stream>>>(gx1, gtmp, gx2, lnf2_g, lnf2_b, 256);
  logits_k<<<CDIV(256*502,256),256,0,stream>>>(gx2, relmem, seqf, logitsb);
  pred_copy<<<CDIV(128*502,256),256,0,stream>>>(logitsb, (float*)d_out);
  final_ent<<<256,256,0,stream>>>(logitsb, lossBase);
}